// Round 7
// baseline (535.784 us; speedup 1.0000x reference)
//
#include <hip/hip_runtime.h>
#include <hip/hip_fp16.h>
#include <math.h>

#define N_USERS 50000
#define N_ENT   100000
#define N_INT   5
#define EMB     128
#define N_REL   20
#define N_EDGES 1000000
#define NNZ     1000000
#define SLOT    64   // max degree; Poisson(10)/Poisson(20) => P(>64) ~ 1e-30
#define NPART   8    // destination partitions (XCD affinity via blockIdx%8)
#define STAGE_CAP 131072   // per-partition staging capacity (expect ~125K, 6-sigma safe)
#define CSTRIDE 32   // cursor padding: 32 ints = 128 B = one full line per counter
#define SITEMS  4    // items per thread in stage_kernel
#define NCH     128  // scatter chunks per partition per type (128*256*4 = 131072 = cap)
#define EBLOCKS (N_ENT/16)    // 6250 entity-gather blocks (4 rows/wave x 4 waves)
#define UBLOCKS (N_USERS/16)  // 3125 user-gather blocks

union F4H8 { float4 f4; __half2 h2[4]; };

// ---------------------------------------------------------------------------
// Distance-correlation, one intent PAIR per block (10 blocks).
// ---------------------------------------------------------------------------
__global__ __launch_bounds__(256) void cor_pair_kernel(const float* __restrict__ intent,
                                                       float* __restrict__ partial) {
    __shared__ float t1[EMB], t2[EMB], rma[EMB], rmb[EMB];
    __shared__ float red[256];
    __shared__ float sh_mean_a, sh_mean_b;
    const int tid = threadIdx.x;
    const int p = blockIdx.x;
    const int pi[10] = {0,0,0,0,1,1,1,2,2,3};
    const int pj[10] = {1,2,3,4,2,3,4,3,4,4};

    if (tid < EMB) {
        t1[tid] = intent[pi[p]*EMB + tid];
        t2[tid] = intent[pj[p]*EMB + tid];
    }
    __syncthreads();
    if (tid < EMB) {
        float x1 = t1[tid], x2 = t2[tid];
        float sa = 0.f, sb = 0.f;
        for (int k = 0; k < EMB; ++k) {
            float da = x1 - t1[k];
            float db = x2 - t2[k];
            sa += sqrtf(da*da + 1e-8f);
            sb += sqrtf(db*db + 1e-8f);
        }
        rma[tid] = sa / (float)EMB;
        rmb[tid] = sb / (float)EMB;
    }
    __syncthreads();
    red[tid] = (tid < EMB) ? rma[tid] : 0.f;
    __syncthreads();
    for (int s = 128; s > 0; s >>= 1) { if (tid < s) red[tid] += red[tid+s]; __syncthreads(); }
    if (tid == 0) sh_mean_a = red[0] / (float)EMB;
    __syncthreads();
    red[tid] = (tid < EMB) ? rmb[tid] : 0.f;
    __syncthreads();
    for (int s = 128; s > 0; s >>= 1) { if (tid < s) red[tid] += red[tid+s]; __syncthreads(); }
    if (tid == 0) sh_mean_b = red[0] / (float)EMB;
    __syncthreads();
    const float mean_a = sh_mean_a, mean_b = sh_mean_b;

    float lab = 0.f, laa = 0.f, lbb = 0.f;
    for (int idx = tid; idx < EMB*EMB; idx += 256) {
        int r = idx >> 7, c = idx & (EMB-1);
        float da = t1[r] - t1[c];
        float db = t2[r] - t2[c];
        float av = sqrtf(da*da + 1e-8f);
        float bv = sqrtf(db*db + 1e-8f);
        float A = av - rma[r] - rma[c] + mean_a;
        float B = bv - rmb[r] - rmb[c] + mean_b;
        lab += A*B; laa += A*A; lbb += B*B;
    }
    red[tid] = lab; __syncthreads();
    for (int s = 128; s > 0; s >>= 1) { if (tid < s) red[tid] += red[tid+s]; __syncthreads(); }
    float sab = red[0]; __syncthreads();
    red[tid] = laa; __syncthreads();
    for (int s = 128; s > 0; s >>= 1) { if (tid < s) red[tid] += red[tid+s]; __syncthreads(); }
    float saa = red[0]; __syncthreads();
    red[tid] = lbb; __syncthreads();
    for (int s = 128; s > 0; s >>= 1) { if (tid < s) red[tid] += red[tid+s]; __syncthreads(); }
    float sbb = red[0]; __syncthreads();

    if (tid == 0) {
        const float d2 = (float)(EMB*EMB);
        float dab = sqrtf(fmaxf(sab/d2, 0.f) + 1e-8f);
        float daa = sqrtf(fmaxf(saa/d2, 0.f) + 1e-8f);
        float dbb = sqrtf(fmaxf(sbb/d2, 0.f) + 1e-8f);
        partial[p] = dab / sqrtf(daa*dbb + 1e-8f);
    }
}

__global__ void cor_sum_kernel(const float* __restrict__ partial, float* __restrict__ out_cor) {
    if (threadIdx.x == 0) {
        float s = 0.f;
        for (int i = 0; i < 10; ++i) s += partial[i];
        out_cor[0] = s;
    }
}

// ---------------------------------------------------------------------------
// intent2[i] = (all_intent[i] + intent[i]) / 2  (loop-invariant)
// ---------------------------------------------------------------------------
__global__ __launch_bounds__(128) void intent2_kernel(const float* __restrict__ intent,
                                                      const float* __restrict__ r_emb,
                                                      float* __restrict__ intent2) {
    const int i = blockIdx.x;
    const int d = threadIdx.x;
    __shared__ float red[EMB];
    __shared__ float dot[N_REL];
    int start, n;
    if      (i == 0) { start = 0;  n = 20; }
    else if (i == 1) { start = 0;  n = 4;  }
    else if (i == 2) { start = 4;  n = 4;  }
    else if (i == 3) { start = 8;  n = 4;  }
    else             { start = 12; n = 8;  }

    const float v = intent[i*EMB + d];
    for (int j = 0; j < n; ++j) {
        red[d] = v * r_emb[(start+j)*EMB + d];
        __syncthreads();
        for (int s = 64; s > 0; s >>= 1) { if (d < s) red[d] += red[d+s]; __syncthreads(); }
        if (d == 0) dot[j] = red[0];
        __syncthreads();
    }
    float m = -1e30f;
    for (int j = 0; j < n; ++j) m = fmaxf(m, dot[j]);
    float s = 0.f;
    float att[N_REL];
    for (int j = 0; j < n; ++j) { att[j] = expf(dot[j] - m); s += att[j]; }
    float out = 0.f;
    for (int j = 0; j < n; ++j) out += (att[j]/s) * r_emb[(start+j)*EMB + d];
    out /= (float)n;
    intent2[i*EMB + d] = 0.5f * (out + v);
}

// ---------------------------------------------------------------------------
// f32 -> f16 conversion of the entity table
// ---------------------------------------------------------------------------
__global__ __launch_bounds__(256) void conv_kernel(const float2* __restrict__ in,
                                                   __half2* __restrict__ out, int n) {
    int i = blockIdx.x*256 + threadIdx.x;
    if (i < n) { float2 v = in[i]; out[i] = __floats2half2_rn(v.x, v.y); }
}

// ---------------------------------------------------------------------------
// Build pass 1: single streaming scan of all 2M items, SITEMS per thread,
// one tile-phase per block. Classify by dest partition, count in LDS,
// reserve global space with ONE atomic per partition per block into a
// line-padded cursor array (16 parallel atomic streams).
// ---------------------------------------------------------------------------
__global__ __launch_bounds__(256) void stage_kernel(const int* __restrict__ head,
                                                    const int* __restrict__ tail,
                                                    const int* __restrict__ etype,
                                                    const int* __restrict__ irows,
                                                    const int* __restrict__ icols,
                                                    const float* __restrict__ ivals,
                                                    int* __restrict__ cursor,
                                                    uint2* __restrict__ stage_e,
                                                    uint2* __restrict__ stage_u) {
    __shared__ int l_cnt[2*NPART];
    __shared__ int l_base[2*NPART];
    const int TOTAL = N_EDGES + NNZ;
    const int tid = threadIdx.x;
    const int base = blockIdx.x * (256*SITEMS);

    if (tid < 2*NPART) l_cnt[tid] = 0;
    __syncthreads();

    int part[SITEMS], loc[SITEMS];
    unsigned w0[SITEMS], w1[SITEMS];
    bool act[SITEMS];
    #pragma unroll
    for (int t = 0; t < SITEMS; ++t) {
        const int i = base + t*256 + tid;   // coalesced per sub-step
        act[t] = i < TOTAL;
        if (act[t]) {
            if (i < N_EDGES) {
                int h = head[i];
                part[t] = h / (N_ENT/NPART);                 // 0..7
                w0[t] = (unsigned)h;
                w1[t] = (unsigned)(tail[i] | ((etype[i]-1) << 20));
            } else {
                int j = i - N_EDGES;
                int r = irows[j];
                part[t] = NPART + r / (N_USERS/NPART);       // 8..15
                unsigned q = (unsigned)(ivals[j]*32767.0f + 0.5f);
                w0[t] = (unsigned)r;
                w1[t] = (q << 17) | (unsigned)icols[j];
            }
            loc[t] = atomicAdd(&l_cnt[part[t]], 1);
        }
    }
    __syncthreads();
    if (tid < 2*NPART && l_cnt[tid] > 0)
        l_base[tid] = atomicAdd(&cursor[tid*CSTRIDE], l_cnt[tid]);
    __syncthreads();
    #pragma unroll
    for (int t = 0; t < SITEMS; ++t) {
        if (act[t]) {
            int pos = l_base[part[t]] + loc[t];
            if (pos < STAGE_CAP) {
                if (part[t] < NPART)
                    stage_e[(size_t)part[t]*STAGE_CAP + pos] = make_uint2(w0[t], w1[t]);
                else
                    stage_u[(size_t)(part[t]-NPART)*STAGE_CAP + pos] = make_uint2(w0[t], w1[t]);
            }
        }
    }
}

// ---------------------------------------------------------------------------
// Build pass 2 (fused e+u): partition = blockIdx%8 (XCD affinity). 4 items
// per thread via 2x uint4 (4 parallel atomic chains -- the scatter is
// latency-bound: occupancy/ILP is the lever, not bandwidth). e-chunks and
// u-chunks in one launch so each type's tail is filled by the other.
// ---------------------------------------------------------------------------
__global__ __launch_bounds__(256) void scatter_kernel(const uint2* __restrict__ stage_e,
                                                      const uint2* __restrict__ stage_u,
                                                      const int* __restrict__ cursor,
                                                      int* __restrict__ cnt_e,
                                                      int* __restrict__ cnt_u,
                                                      int* __restrict__ sorted_e,
                                                      unsigned* __restrict__ sorted_u) {
    const int part = blockIdx.x & (NPART-1);
    const int cid  = blockIdx.x >> 3;          // 0..2*NCH-1
    const bool isE = cid < NCH;
    const int chunk = isE ? cid : cid - NCH;
    const int n = min(cursor[(isE ? part : NPART + part)*CSTRIDE], STAGE_CAP);
    const uint2* s = (isE ? stage_e : stage_u) + (size_t)part*STAGE_CAP;
    int* cnt = isE ? cnt_e : cnt_u;

    const int i0 = (chunk*256 + threadIdx.x) * 4;
    if (i0 >= n) return;
    const bool h1 = i0 + 1 < n, h2 = i0 + 2 < n, h3 = i0 + 3 < n;
    uint4 a = *(const uint4*)(s + i0);         // 16B aligned (i0 multiple of 4)
    uint4 b;
    if (h2) b = *(const uint4*)(s + i0 + 2);
    int pos0 = atomicAdd(&cnt[a.x], 1);
    int pos1 = h1 ? atomicAdd(&cnt[a.z], 1) : 0;
    int pos2 = h2 ? atomicAdd(&cnt[b.x], 1) : 0;
    int pos3 = h3 ? atomicAdd(&cnt[b.z], 1) : 0;
    if (isE) {
        if (pos0 < SLOT)       sorted_e[(size_t)a.x*SLOT + pos0] = (int)a.y;
        if (h1 && pos1 < SLOT) sorted_e[(size_t)a.z*SLOT + pos1] = (int)a.w;
        if (h2 && pos2 < SLOT) sorted_e[(size_t)b.x*SLOT + pos2] = (int)b.y;
        if (h3 && pos3 < SLOT) sorted_e[(size_t)b.z*SLOT + pos3] = (int)b.w;
    } else {
        if (pos0 < SLOT)       sorted_u[(size_t)a.x*SLOT + pos0] = a.y;
        if (h1 && pos1 < SLOT) sorted_u[(size_t)a.z*SLOT + pos1] = a.w;
        if (h2 && pos2 < SLOT) sorted_u[(size_t)b.x*SLOT + pos2] = b.y;
        if (h3 && pos3 < SLOT) sorted_u[(size_t)b.z*SLOT + pos3] = b.w;
    }
}

// ---------------------------------------------------------------------------
// FUSED per-hop gather, FOUR ROWS PER WAVE (L3-hit latency-bound: 8 gather
// loads in flight per lane vs 4). Blocks [0, EBLOCKS) entity, rest user.
// Per-row edge order identical to the 1/2-row versions -> bit-identical.
// Entity epilogue: group g handles row g. User epilogue: double-pass LDS
// transpose (2 slots) + 4 independent softmax-gate chains.
// ---------------------------------------------------------------------------
__global__ __launch_bounds__(256) void gather_eu_kernel(const __half2* __restrict__ e_tab,
                                                        const int* __restrict__ cnt_e,
                                                        const int* __restrict__ sorted_e,
                                                        const float* __restrict__ r_emb,
                                                        const float2* __restrict__ base_e,
                                                        float2* __restrict__ res_e,
                                                        __half2* __restrict__ e_out,
                                                        const int* __restrict__ cnt_u,
                                                        const unsigned* __restrict__ sorted_u,
                                                        const float2* __restrict__ u_prev,
                                                        const float* __restrict__ i2,
                                                        const float2* __restrict__ base_u,
                                                        float2* __restrict__ res_u,
                                                        float2* __restrict__ u_out,
                                                        int store, int write_res) {
    __shared__ float2 s_i2[N_INT*64];
    __shared__ float  tr[4][2][132];

    const int wv   = threadIdx.x >> 6;
    const int lane = threadIdx.x & 63;
    const int g = lane >> 4, sl = lane & 15;
    const float4* e4 = (const float4*)e_tab;   // row stride = 16 float4

    if (blockIdx.x < EBLOCKS) {
        // ================= ENTITY GATHER (no LDS, no barrier) ==============
        const int row0 = blockIdx.x*16 + wv*4;
        const int row1 = row0 + 1, row2 = row0 + 2, row3 = row0 + 3;
        const int deg0 = min(cnt_e[row0], SLOT);
        const int deg1 = min(cnt_e[row1], SLOT);
        const int deg2 = min(cnt_e[row2], SLOT);
        const int deg3 = min(cnt_e[row3], SLOT);
        int p0 = (lane < deg0) ? sorted_e[(size_t)row0*SLOT + lane] : 0;
        int p1 = (lane < deg1) ? sorted_e[(size_t)row1*SLOT + lane] : 0;
        int p2 = (lane < deg2) ? sorted_e[(size_t)row2*SLOT + lane] : 0;
        int p3 = (lane < deg3) ? sorted_e[(size_t)row3*SLOT + lane] : 0;

        const float4* r4 = (const float4*)r_emb;  // row stride = 32 float4
        float accA[8] = {0,0,0,0,0,0,0,0};
        float accB[8] = {0,0,0,0,0,0,0,0};
        float accC[8] = {0,0,0,0,0,0,0,0};
        float accD[8] = {0,0,0,0,0,0,0,0};

#define EFMA(ACC, RAW, PM) do { \
            F4H8 u_; u_.f4 = (RAW); \
            const __half* h_ = (const __half*)u_.h2; \
            const int rr_ = (PM) >> 20; \
            float4 w0_ = r4[rr_*32 + sl*2]; \
            float4 w1_ = r4[rr_*32 + sl*2 + 1]; \
            ACC[0] += __half2float(h_[0]) * w0_.x; \
            ACC[1] += __half2float(h_[1]) * w0_.y; \
            ACC[2] += __half2float(h_[2]) * w0_.z; \
            ACC[3] += __half2float(h_[3]) * w0_.w; \
            ACC[4] += __half2float(h_[4]) * w1_.x; \
            ACC[5] += __half2float(h_[5]) * w1_.y; \
            ACC[6] += __half2float(h_[6]) * w1_.z; \
            ACC[7] += __half2float(h_[7]) * w1_.w; \
        } while (0)

        const int dm = max(max(deg0, deg1), max(deg2, deg3));
        for (int k = 0; k < dm; k += 8) {
            const int meA = k + g, meB = k + 4 + g;
            const int pm00 = __shfl(p0, meA), pm01 = __shfl(p0, meB);
            const int pm10 = __shfl(p1, meA), pm11 = __shfl(p1, meB);
            const int pm20 = __shfl(p2, meA), pm21 = __shfl(p2, meB);
            const int pm30 = __shfl(p3, meA), pm31 = __shfl(p3, meB);
            const bool a00 = meA < deg0, a01 = meB < deg0;
            const bool a10 = meA < deg1, a11 = meB < deg1;
            const bool a20 = meA < deg2, a21 = meB < deg2;
            const bool a30 = meA < deg3, a31 = meB < deg3;
            float4 r00, r01, r10, r11, r20, r21, r30, r31;
            if (a00) r00 = e4[(size_t)(pm00 & 0xFFFFF)*16 + sl];
            if (a01) r01 = e4[(size_t)(pm01 & 0xFFFFF)*16 + sl];
            if (a10) r10 = e4[(size_t)(pm10 & 0xFFFFF)*16 + sl];
            if (a11) r11 = e4[(size_t)(pm11 & 0xFFFFF)*16 + sl];
            if (a20) r20 = e4[(size_t)(pm20 & 0xFFFFF)*16 + sl];
            if (a21) r21 = e4[(size_t)(pm21 & 0xFFFFF)*16 + sl];
            if (a30) r30 = e4[(size_t)(pm30 & 0xFFFFF)*16 + sl];
            if (a31) r31 = e4[(size_t)(pm31 & 0xFFFFF)*16 + sl];
            if (a00) EFMA(accA, r00, pm00);
            if (a01) EFMA(accA, r01, pm01);
            if (a10) EFMA(accB, r10, pm10);
            if (a11) EFMA(accB, r11, pm11);
            if (a20) EFMA(accC, r20, pm20);
            if (a21) EFMA(accC, r21, pm21);
            if (a30) EFMA(accD, r30, pm30);
            if (a31) EFMA(accD, r31, pm31);
        }
#undef EFMA

        #pragma unroll
        for (int j = 0; j < 8; ++j) {
            accA[j] += __shfl_xor(accA[j], 16); accA[j] += __shfl_xor(accA[j], 32);
            accB[j] += __shfl_xor(accB[j], 16); accB[j] += __shfl_xor(accB[j], 32);
            accC[j] += __shfl_xor(accC[j], 16); accC[j] += __shfl_xor(accC[j], 32);
            accD[j] += __shfl_xor(accD[j], 16); accD[j] += __shfl_xor(accD[j], 32);
        }
        const float invA = (deg0 > 0) ? 1.0f/(float)deg0 : 0.0f;
        const float invB = (deg1 > 0) ? 1.0f/(float)deg1 : 0.0f;
        const float invC = (deg2 > 0) ? 1.0f/(float)deg2 : 0.0f;
        const float invD = (deg3 > 0) ? 1.0f/(float)deg3 : 0.0f;
        float ssA = 0.f, ssB = 0.f, ssC = 0.f, ssD = 0.f;
        #pragma unroll
        for (int j = 0; j < 8; ++j) {
            accA[j] *= invA; ssA += accA[j]*accA[j];
            accB[j] *= invB; ssB += accB[j]*accB[j];
            accC[j] *= invC; ssC += accC[j]*accC[j];
            accD[j] *= invD; ssD += accD[j]*accD[j];
        }
        #pragma unroll
        for (int o = 8; o > 0; o >>= 1) {   // within 16-lane group
            ssA += __shfl_xor(ssA, o);
            ssB += __shfl_xor(ssB, o);
            ssC += __shfl_xor(ssC, o);
            ssD += __shfl_xor(ssD, o);
        }
        const float invnA = 1.0f / fmaxf(sqrtf(ssA), 1e-12f);
        const float invnB = 1.0f / fmaxf(sqrtf(ssB), 1e-12f);
        const float invnC = 1.0f / fmaxf(sqrtf(ssC), 1e-12f);
        const float invnD = 1.0f / fmaxf(sqrtf(ssD), 1e-12f);
        #pragma unroll
        for (int j = 0; j < 8; ++j) {
            accA[j] *= invnA; accB[j] *= invnB; accC[j] *= invnC; accD[j] *= invnD;
        }

#define EPI(ROW, ACC) do { \
            size_t r16 = (size_t)(ROW)*16 + sl; \
            if (store) { \
                F4H8 u_; \
                u_.h2[0] = __floats2half2_rn(ACC[0], ACC[1]); \
                u_.h2[1] = __floats2half2_rn(ACC[2], ACC[3]); \
                u_.h2[2] = __floats2half2_rn(ACC[4], ACC[5]); \
                u_.h2[3] = __floats2half2_rn(ACC[6], ACC[7]); \
                ((float4*)e_out)[r16] = u_.f4; \
            } \
            if (write_res) { \
                F4H8 pv; pv.f4 = ((const float4*)e_tab)[r16]; \
                const float4* b4 = (const float4*)base_e; \
                float4 ba = b4[(size_t)(ROW)*32 + sl*2]; \
                float4 bb = b4[(size_t)(ROW)*32 + sl*2 + 1]; \
                float2 q0 = __half22float2(pv.h2[0]); \
                float2 q1 = __half22float2(pv.h2[1]); \
                float2 q2 = __half22float2(pv.h2[2]); \
                float2 q3 = __half22float2(pv.h2[3]); \
                float4 ra = make_float4(ba.x + q0.x + ACC[0], ba.y + q0.y + ACC[1], \
                                        ba.z + q1.x + ACC[2], ba.w + q1.y + ACC[3]); \
                float4 rb = make_float4(bb.x + q2.x + ACC[4], bb.y + q2.y + ACC[5], \
                                        bb.z + q3.x + ACC[6], bb.w + q3.y + ACC[7]); \
                ((float4*)res_e)[(size_t)(ROW)*32 + sl*2]     = ra; \
                ((float4*)res_e)[(size_t)(ROW)*32 + sl*2 + 1] = rb; \
            } \
        } while (0)

        if (g == 0)      EPI(row0, accA);
        else if (g == 1) EPI(row1, accB);
        else if (g == 2) EPI(row2, accC);
        else             EPI(row3, accD);
#undef EPI
    } else {
        // ================= USER GATHER =====================================
        for (int k = threadIdx.x; k < N_INT*64; k += 256) s_i2[k] = ((const float2*)i2)[k];
        __syncthreads();
        const int ub = blockIdx.x - EBLOCKS;
        const int row0 = ub*16 + wv*4;
        const int row1 = row0 + 1, row2 = row0 + 2, row3 = row0 + 3;
        const int deg0 = min(cnt_u[row0], SLOT);
        const int deg1 = min(cnt_u[row1], SLOT);
        const int deg2 = min(cnt_u[row2], SLOT);
        const int deg3 = min(cnt_u[row3], SLOT);
        unsigned p0 = (lane < deg0) ? sorted_u[(size_t)row0*SLOT + lane] : 0u;
        unsigned p1 = (lane < deg1) ? sorted_u[(size_t)row1*SLOT + lane] : 0u;
        unsigned p2 = (lane < deg2) ? sorted_u[(size_t)row2*SLOT + lane] : 0u;
        unsigned p3 = (lane < deg3) ? sorted_u[(size_t)row3*SLOT + lane] : 0u;

        const float qs = 1.0f/32767.0f;
        float accA[8] = {0,0,0,0,0,0,0,0};
        float accB[8] = {0,0,0,0,0,0,0,0};
        float accC[8] = {0,0,0,0,0,0,0,0};
        float accD[8] = {0,0,0,0,0,0,0,0};

#define UFMA(ACC, RAW, Q) do { \
            F4H8 u_; u_.f4 = (RAW); \
            const __half* h_ = (const __half*)u_.h2; \
            const float v_ = (float)((Q) >> 17) * qs; \
            ACC[0] += v_ * __half2float(h_[0]); \
            ACC[1] += v_ * __half2float(h_[1]); \
            ACC[2] += v_ * __half2float(h_[2]); \
            ACC[3] += v_ * __half2float(h_[3]); \
            ACC[4] += v_ * __half2float(h_[4]); \
            ACC[5] += v_ * __half2float(h_[5]); \
            ACC[6] += v_ * __half2float(h_[6]); \
            ACC[7] += v_ * __half2float(h_[7]); \
        } while (0)

        const int dm = max(max(deg0, deg1), max(deg2, deg3));
        for (int k = 0; k < dm; k += 8) {
            const int meA = k + g, meB = k + 4 + g;
            const unsigned q00 = __shfl(p0, meA), q01 = __shfl(p0, meB);
            const unsigned q10 = __shfl(p1, meA), q11 = __shfl(p1, meB);
            const unsigned q20 = __shfl(p2, meA), q21 = __shfl(p2, meB);
            const unsigned q30 = __shfl(p3, meA), q31 = __shfl(p3, meB);
            const bool a00 = meA < deg0, a01 = meB < deg0;
            const bool a10 = meA < deg1, a11 = meB < deg1;
            const bool a20 = meA < deg2, a21 = meB < deg2;
            const bool a30 = meA < deg3, a31 = meB < deg3;
            float4 r00, r01, r10, r11, r20, r21, r30, r31;
            if (a00) r00 = e4[(size_t)(q00 & 0x1FFFFu)*16 + sl];
            if (a01) r01 = e4[(size_t)(q01 & 0x1FFFFu)*16 + sl];
            if (a10) r10 = e4[(size_t)(q10 & 0x1FFFFu)*16 + sl];
            if (a11) r11 = e4[(size_t)(q11 & 0x1FFFFu)*16 + sl];
            if (a20) r20 = e4[(size_t)(q20 & 0x1FFFFu)*16 + sl];
            if (a21) r21 = e4[(size_t)(q21 & 0x1FFFFu)*16 + sl];
            if (a30) r30 = e4[(size_t)(q30 & 0x1FFFFu)*16 + sl];
            if (a31) r31 = e4[(size_t)(q31 & 0x1FFFFu)*16 + sl];
            if (a00) UFMA(accA, r00, q00);
            if (a01) UFMA(accA, r01, q01);
            if (a10) UFMA(accB, r10, q10);
            if (a11) UFMA(accB, r11, q11);
            if (a20) UFMA(accC, r20, q20);
            if (a21) UFMA(accC, r21, q21);
            if (a30) UFMA(accD, r30, q30);
            if (a31) UFMA(accD, r31, q31);
        }
#undef UFMA

        #pragma unroll
        for (int j = 0; j < 8; ++j) {
            accA[j] += __shfl_xor(accA[j], 16); accA[j] += __shfl_xor(accA[j], 32);
            accB[j] += __shfl_xor(accB[j], 16); accB[j] += __shfl_xor(accB[j], 32);
            accC[j] += __shfl_xor(accC[j], 16); accC[j] += __shfl_xor(accC[j], 32);
            accD[j] += __shfl_xor(accD[j], 16); accD[j] += __shfl_xor(accD[j], 32);
        }
        // transpose pass A (rows 0,1): sl-layout -> float2 layout
        if (g == 0) {
            #pragma unroll
            for (int j = 0; j < 8; ++j) tr[wv][0][sl*8 + j] = accA[j];
        } else if (g == 1) {
            #pragma unroll
            for (int j = 0; j < 8; ++j) tr[wv][1][sl*8 + j] = accB[j];
        }
        __syncthreads();
        const float s00 = tr[wv][0][2*lane], s01 = tr[wv][0][2*lane + 1];
        const float s10 = tr[wv][1][2*lane], s11 = tr[wv][1][2*lane + 1];
        __syncthreads();
        // transpose pass B (rows 2,3)
        if (g == 0) {
            #pragma unroll
            for (int j = 0; j < 8; ++j) tr[wv][0][sl*8 + j] = accC[j];
        } else if (g == 1) {
            #pragma unroll
            for (int j = 0; j < 8; ++j) tr[wv][1][sl*8 + j] = accD[j];
        }
        __syncthreads();
        const float s20 = tr[wv][0][2*lane], s21 = tr[wv][0][2*lane + 1];
        const float s30 = tr[wv][1][2*lane], s31 = tr[wv][1][2*lane + 1];

        const size_t o0 = (size_t)row0*64 + lane;
        const size_t o1 = (size_t)row1*64 + lane;
        const size_t o2 = (size_t)row2*64 + lane;
        const size_t o3 = (size_t)row3*64 + lane;
        const float2 up0 = u_prev[o0];
        const float2 up1 = u_prev[o1];
        const float2 up2 = u_prev[o2];
        const float2 up3 = u_prev[o3];
        float dot0[N_INT], dot1[N_INT], dot2[N_INT], dot3[N_INT];
        #pragma unroll
        for (int i = 0; i < N_INT; ++i) {
            float2 w = s_i2[i*64 + lane];
            float pr0 = up0.x*w.x + up0.y*w.y;
            float pr1 = up1.x*w.x + up1.y*w.y;
            float pr2 = up2.x*w.x + up2.y*w.y;
            float pr3 = up3.x*w.x + up3.y*w.y;
            #pragma unroll
            for (int o = 32; o > 0; o >>= 1) {
                pr0 += __shfl_xor(pr0, o);
                pr1 += __shfl_xor(pr1, o);
                pr2 += __shfl_xor(pr2, o);
                pr3 += __shfl_xor(pr3, o);
            }
            dot0[i] = pr0; dot1[i] = pr1; dot2[i] = pr2; dot3[i] = pr3;
        }
        float m0 = dot0[0], m1 = dot1[0], m2 = dot2[0], m3 = dot3[0];
        #pragma unroll
        for (int i = 1; i < N_INT; ++i) {
            m0 = fmaxf(m0, dot0[i]); m1 = fmaxf(m1, dot1[i]);
            m2 = fmaxf(m2, dot2[i]); m3 = fmaxf(m3, dot3[i]);
        }
        float sm0 = 0.f, sm1 = 0.f, sm2 = 0.f, sm3 = 0.f;
        #pragma unroll
        for (int i = 0; i < N_INT; ++i) {
            dot0[i] = expf(dot0[i] - m0); sm0 += dot0[i];
            dot1[i] = expf(dot1[i] - m1); sm1 += dot1[i];
            dot2[i] = expf(dot2[i] - m2); sm2 += dot2[i];
            dot3[i] = expf(dot3[i] - m3); sm3 += dot3[i];
        }
        float f00 = 0.f, f01 = 0.f, f10 = 0.f, f11 = 0.f;
        float f20 = 0.f, f21 = 0.f, f30 = 0.f, f31 = 0.f;
        #pragma unroll
        for (int i = 0; i < N_INT; ++i) {
            float a0 = dot0[i] / sm0;
            float a1 = dot1[i] / sm1;
            float a2 = dot2[i] / sm2;
            float a3 = dot3[i] / sm3;
            float2 w = s_i2[i*64 + lane];
            f00 += a0*w.x; f01 += a0*w.y;
            f10 += a1*w.x; f11 += a1*w.y;
            f20 += a2*w.x; f21 += a2*w.y;
            f30 += a3*w.x; f31 += a3*w.y;
        }
        float x00 = s00 * (1.0f + f00), x01 = s01 * (1.0f + f01);
        float x10 = s10 * (1.0f + f10), x11 = s11 * (1.0f + f11);
        float x20 = s20 * (1.0f + f20), x21 = s21 * (1.0f + f21);
        float x30 = s30 * (1.0f + f30), x31 = s31 * (1.0f + f31);
        float ss0 = x00*x00 + x01*x01;
        float ss1 = x10*x10 + x11*x11;
        float ss2 = x20*x20 + x21*x21;
        float ss3 = x30*x30 + x31*x31;
        #pragma unroll
        for (int o = 32; o > 0; o >>= 1) {
            ss0 += __shfl_xor(ss0, o);
            ss1 += __shfl_xor(ss1, o);
            ss2 += __shfl_xor(ss2, o);
            ss3 += __shfl_xor(ss3, o);
        }
        const float invn0 = 1.0f / fmaxf(sqrtf(ss0), 1e-12f);
        const float invn1 = 1.0f / fmaxf(sqrtf(ss1), 1e-12f);
        const float invn2 = 1.0f / fmaxf(sqrtf(ss2), 1e-12f);
        const float invn3 = 1.0f / fmaxf(sqrtf(ss3), 1e-12f);
        x00 *= invn0; x01 *= invn0;
        x10 *= invn1; x11 *= invn1;
        x20 *= invn2; x21 *= invn2;
        x30 *= invn3; x31 *= invn3;
        if (store) {
            u_out[o0] = make_float2(x00, x01);
            u_out[o1] = make_float2(x10, x11);
            u_out[o2] = make_float2(x20, x21);
            u_out[o3] = make_float2(x30, x31);
        }
        if (write_res) {
            float2 b0 = base_u[o0];
            float2 b1 = base_u[o1];
            float2 b2 = base_u[o2];
            float2 b3 = base_u[o3];
            res_u[o0] = make_float2(b0.x + up0.x + x00, b0.y + up0.y + x01);
            res_u[o1] = make_float2(b1.x + up1.x + x10, b1.y + up1.y + x11);
            res_u[o2] = make_float2(b2.x + up2.x + x20, b2.y + up2.y + x21);
            res_u[o3] = make_float2(b3.x + up3.x + x30, b3.y + up3.y + x31);
        }
    }
}

// ---------------------------------------------------------------------------
extern "C" void kernel_launch(void* const* d_in, const int* in_sizes, int n_in,
                              void* d_out, int out_size, void* d_ws, size_t ws_size,
                              hipStream_t stream) {
    const float* user_emb   = (const float*)d_in[0];
    const float* entity_emb = (const float*)d_in[1];
    const float* intent_emb = (const float*)d_in[2];
    const int*   edge_index = (const int*)  d_in[3];
    const int*   edge_type  = (const int*)  d_in[4];
    const int*   irows      = (const int*)  d_in[5];
    const int*   icols      = (const int*)  d_in[6];
    const float* ivals      = (const float*)d_in[7];
    const float* r_emb      = (const float*)d_in[8];

    float* out     = (float*)d_out;
    float* res_e   = out;
    float* res_u   = out + (size_t)N_ENT*EMB;
    float* out_cor = out + (size_t)N_ENT*EMB + (size_t)N_USERS*EMB;

    const int* head = edge_index;
    const int* tail = edge_index + N_EDGES;

    char* ws = (char*)d_ws;
    __half2* entF16 = (__half2*)ws;  ws += (size_t)N_ENT*EMB*2;
    __half2* eA     = (__half2*)ws;  ws += (size_t)N_ENT*EMB*2;
    float2*  uA     = (float2*)ws;   ws += (size_t)N_USERS*EMB*4;
    int*     sorted_e = (int*)ws;    ws += (size_t)N_ENT*SLOT*4;
    unsigned* sorted_u = (unsigned*)ws; ws += (size_t)N_USERS*SLOT*4;
    int* cnt_e = (int*)ws;           ws += (size_t)N_ENT*4;
    int* cnt_u = (int*)ws;           ws += (size_t)N_USERS*4;
    float* i2  = (float*)ws;         ws += N_INT*EMB*4;
    float* ws_cor = (float*)ws;      ws += 16*4;
    int* cursor = (int*)ws;          ws += 2*NPART*CSTRIDE*4;

    // staging aliases eA/uA: both are dead until gather hop 1 writes them,
    // and the scatter kernel (the consumer) completes before that on stream.
    uint2* stage_e = (uint2*)eA;     // 8 MB <= 25.6 MB region
    uint2* stage_u = (uint2*)uA;     // 8 MB <= 25.6 MB region

    hipMemsetAsync(cnt_e, 0, (size_t)N_ENT*4, stream);
    hipMemsetAsync(cnt_u, 0, (size_t)N_USERS*4, stream);
    hipMemsetAsync(cursor, 0, 2*NPART*CSTRIDE*4, stream);

    cor_pair_kernel<<<10, 256, 0, stream>>>(intent_emb, ws_cor);
    cor_sum_kernel<<<1, 64, 0, stream>>>(ws_cor, out_cor);
    intent2_kernel<<<N_INT, 128, 0, stream>>>(intent_emb, r_emb, i2);
    conv_kernel<<<(N_ENT*64 + 255)/256, 256, 0, stream>>>((const float2*)entity_emb, entF16, N_ENT*64);

    // 2048 blocks x 256 threads x 4 items = 2,097,152 >= 2,000,000: one phase
    stage_kernel<<<2048, 256, 0, stream>>>(head, tail, edge_type,
                                           irows, icols, ivals,
                                           cursor, stage_e, stage_u);
    // fused e+u scatter, 4 items/thread (4 parallel atomic chains)
    scatter_kernel<<<NPART*2*NCH, 256, 0, stream>>>(stage_e, stage_u, cursor,
                                                    cnt_e, cnt_u, sorted_e, sorted_u);

    const float2* ent2 = (const float2*)entity_emb;
    const float2* usr2 = (const float2*)user_emb;

    // hop 1 (fused e+u): store eA(f16)/uA(f32), no residual traffic
    gather_eu_kernel<<<EBLOCKS + UBLOCKS, 256, 0, stream>>>(
        entF16, cnt_e, sorted_e, r_emb, ent2, (float2*)res_e, eA,
        cnt_u, sorted_u, usr2, i2, usr2, (float2*)res_u, uA, 1, 0);

    // hop 2 (fused e+u): res = base + prev + x
    gather_eu_kernel<<<EBLOCKS + UBLOCKS, 256, 0, stream>>>(
        eA, cnt_e, sorted_e, r_emb, ent2, (float2*)res_e, eA,
        cnt_u, sorted_u, (const float2*)uA, i2, usr2, (float2*)res_u, uA, 0, 1);
}

// Round 8
// 449.788 us; speedup vs baseline: 1.1912x; 1.1912x over previous
//
#include <hip/hip_runtime.h>
#include <hip/hip_fp16.h>
#include <math.h>

#define N_USERS 50000
#define N_ENT   100000
#define N_INT   5
#define EMB     128
#define N_REL   20
#define N_EDGES 1000000
#define NNZ     1000000
#define SLOT    64   // max degree; Poisson(10)/Poisson(20) => P(>64) ~ 1e-30
#define NPART   8    // destination partitions (XCD affinity via blockIdx%8)
#define STAGE_CAP 131072   // per-partition staging capacity (expect ~125K, 6-sigma safe)
#define CSTRIDE 32   // cursor padding: 32 ints = 128 B = one full line per counter
#define SITEMS  4    // items per thread in stage portion
#define NCH     128  // scatter chunks per partition per type (128*256*4 = 131072 = cap)
#define EBLOCKS (N_ENT/8)    // 12500 entity-gather blocks (2 rows/wave x 4 waves)
#define UBLOCKS (N_USERS/8)  // 6250 user-gather blocks

// misc_kernel block ranges
#define CORB    10                 // cor pair blocks
#define I2END   (CORB + N_INT)     // 15: intent2 blocks
#define CONVBLK 3125               // conv blocks: 3125*2048 float2 = 6.4M exactly
#define CONVEND (I2END + CONVBLK)  // 3140
#define STAGBLK 2048               // stage blocks: 2048*1024 items >= 2M
#define MISCGRID (CONVEND + STAGBLK)  // 5188

union F4H8 { float4 f4; __half2 h2[4]; };

// ---------------------------------------------------------------------------
// MISC mega-kernel: cor pairs (+last-block sum), intent2, f32->f16 conv,
// and the bucket-staging scan -- all mutually independent, one launch.
// ---------------------------------------------------------------------------
__global__ __launch_bounds__(256) void misc_kernel(const float* __restrict__ intent,
                                                   const float* __restrict__ r_emb,
                                                   float* __restrict__ i2,
                                                   float* __restrict__ partial,
                                                   float* __restrict__ out_cor,
                                                   int* __restrict__ done,
                                                   const float2* __restrict__ conv_in,
                                                   __half2* __restrict__ conv_out,
                                                   const int* __restrict__ head,
                                                   const int* __restrict__ tail,
                                                   const int* __restrict__ etype,
                                                   const int* __restrict__ irows,
                                                   const int* __restrict__ icols,
                                                   const float* __restrict__ ivals,
                                                   int* __restrict__ cursor,
                                                   uint2* __restrict__ stage_e,
                                                   uint2* __restrict__ stage_u) {
    __shared__ float t1[EMB], t2[EMB], rma[EMB], rmb[EMB];
    __shared__ float red[256];
    __shared__ float sh_mean_a, sh_mean_b;
    __shared__ float dotsh[N_REL];
    __shared__ int l_cnt[2*NPART];
    __shared__ int l_base[2*NPART];
    const int tid = threadIdx.x;

    if (blockIdx.x < CORB) {
        // ================= COR PAIR (10 blocks) ============================
        const int p = blockIdx.x;
        const int pi[10] = {0,0,0,0,1,1,1,2,2,3};
        const int pj[10] = {1,2,3,4,2,3,4,3,4,4};

        if (tid < EMB) {
            t1[tid] = intent[pi[p]*EMB + tid];
            t2[tid] = intent[pj[p]*EMB + tid];
        }
        __syncthreads();
        if (tid < EMB) {
            float x1 = t1[tid], x2 = t2[tid];
            float sa = 0.f, sb = 0.f;
            for (int k = 0; k < EMB; ++k) {
                float da = x1 - t1[k];
                float db = x2 - t2[k];
                sa += sqrtf(da*da + 1e-8f);
                sb += sqrtf(db*db + 1e-8f);
            }
            rma[tid] = sa / (float)EMB;
            rmb[tid] = sb / (float)EMB;
        }
        __syncthreads();
        red[tid] = (tid < EMB) ? rma[tid] : 0.f;
        __syncthreads();
        for (int s = 128; s > 0; s >>= 1) { if (tid < s) red[tid] += red[tid+s]; __syncthreads(); }
        if (tid == 0) sh_mean_a = red[0] / (float)EMB;
        __syncthreads();
        red[tid] = (tid < EMB) ? rmb[tid] : 0.f;
        __syncthreads();
        for (int s = 128; s > 0; s >>= 1) { if (tid < s) red[tid] += red[tid+s]; __syncthreads(); }
        if (tid == 0) sh_mean_b = red[0] / (float)EMB;
        __syncthreads();
        const float mean_a = sh_mean_a, mean_b = sh_mean_b;

        float lab = 0.f, laa = 0.f, lbb = 0.f;
        for (int idx = tid; idx < EMB*EMB; idx += 256) {
            int r = idx >> 7, c = idx & (EMB-1);
            float da = t1[r] - t1[c];
            float db = t2[r] - t2[c];
            float av = sqrtf(da*da + 1e-8f);
            float bv = sqrtf(db*db + 1e-8f);
            float A = av - rma[r] - rma[c] + mean_a;
            float B = bv - rmb[r] - rmb[c] + mean_b;
            lab += A*B; laa += A*A; lbb += B*B;
        }
        red[tid] = lab; __syncthreads();
        for (int s = 128; s > 0; s >>= 1) { if (tid < s) red[tid] += red[tid+s]; __syncthreads(); }
        float sab = red[0]; __syncthreads();
        red[tid] = laa; __syncthreads();
        for (int s = 128; s > 0; s >>= 1) { if (tid < s) red[tid] += red[tid+s]; __syncthreads(); }
        float saa = red[0]; __syncthreads();
        red[tid] = lbb; __syncthreads();
        for (int s = 128; s > 0; s >>= 1) { if (tid < s) red[tid] += red[tid+s]; __syncthreads(); }
        float sbb = red[0]; __syncthreads();

        if (tid == 0) {
            const float d2 = (float)(EMB*EMB);
            float dab = sqrtf(fmaxf(sab/d2, 0.f) + 1e-8f);
            float daa = sqrtf(fmaxf(saa/d2, 0.f) + 1e-8f);
            float dbb = sqrtf(fmaxf(sbb/d2, 0.f) + 1e-8f);
            partial[p] = dab / sqrtf(daa*dbb + 1e-8f);
            __threadfence();
            int t = atomicAdd(done, 1);
            if (t == CORB - 1) {   // last cor block sums (fences + device atomics)
                float s = 0.f;
                volatile float* vp = (volatile float*)partial;
                for (int i = 0; i < CORB; ++i) s += vp[i];
                out_cor[0] = s;
            }
        }
    } else if (blockIdx.x < I2END) {
        // ================= INTENT2 (5 blocks, 256 thr, d<128 active) =======
        const int i = blockIdx.x - CORB;
        const int d = tid;
        int start, n;
        if      (i == 0) { start = 0;  n = 20; }
        else if (i == 1) { start = 0;  n = 4;  }
        else if (i == 2) { start = 4;  n = 4;  }
        else if (i == 3) { start = 8;  n = 4;  }
        else             { start = 12; n = 8;  }

        const float v = (d < EMB) ? intent[i*EMB + d] : 0.f;
        for (int j = 0; j < n; ++j) {
            if (d < EMB) red[d] = v * r_emb[(start+j)*EMB + d];
            __syncthreads();
            for (int s = 64; s > 0; s >>= 1) { if (d < s) red[d] += red[d+s]; __syncthreads(); }
            if (d == 0) dotsh[j] = red[0];
            __syncthreads();
        }
        if (d < EMB) {
            float m = -1e30f;
            for (int j = 0; j < n; ++j) m = fmaxf(m, dotsh[j]);
            float s = 0.f;
            float att[N_REL];
            for (int j = 0; j < n; ++j) { att[j] = expf(dotsh[j] - m); s += att[j]; }
            float out = 0.f;
            for (int j = 0; j < n; ++j) out += (att[j]/s) * r_emb[(start+j)*EMB + d];
            out /= (float)n;
            i2[i*EMB + d] = 0.5f * (out + v);
        }
    } else if (blockIdx.x < CONVEND) {
        // ================= CONV f32->f16 (3125 blocks x 2048 float2) =======
        const int base = (blockIdx.x - I2END) * 2048;
        #pragma unroll
        for (int t = 0; t < 8; ++t) {
            int idx = base + t*256 + tid;
            float2 v = conv_in[idx];
            conv_out[idx] = __floats2half2_rn(v.x, v.y);
        }
    } else {
        // ================= STAGE (2048 blocks x 1024 items) ================
        const int TOTAL = N_EDGES + NNZ;
        const int base = (blockIdx.x - CONVEND) * (256*SITEMS);

        if (tid < 2*NPART) l_cnt[tid] = 0;
        __syncthreads();

        int part[SITEMS], loc[SITEMS];
        unsigned w0[SITEMS], w1[SITEMS];
        bool act[SITEMS];
        #pragma unroll
        for (int t = 0; t < SITEMS; ++t) {
            const int i = base + t*256 + tid;   // coalesced per sub-step
            act[t] = i < TOTAL;
            if (act[t]) {
                if (i < N_EDGES) {
                    int h = head[i];
                    part[t] = h / (N_ENT/NPART);                 // 0..7
                    w0[t] = (unsigned)h;
                    w1[t] = (unsigned)(tail[i] | ((etype[i]-1) << 20));
                } else {
                    int j = i - N_EDGES;
                    int r = irows[j];
                    part[t] = NPART + r / (N_USERS/NPART);       // 8..15
                    unsigned q = (unsigned)(ivals[j]*32767.0f + 0.5f);
                    w0[t] = (unsigned)r;
                    w1[t] = (q << 17) | (unsigned)icols[j];
                }
                loc[t] = atomicAdd(&l_cnt[part[t]], 1);
            }
        }
        __syncthreads();
        if (tid < 2*NPART && l_cnt[tid] > 0)
            l_base[tid] = atomicAdd(&cursor[tid*CSTRIDE], l_cnt[tid]);
        __syncthreads();
        #pragma unroll
        for (int t = 0; t < SITEMS; ++t) {
            if (act[t]) {
                int pos = l_base[part[t]] + loc[t];
                if (pos < STAGE_CAP) {
                    if (part[t] < NPART)
                        stage_e[(size_t)part[t]*STAGE_CAP + pos] = make_uint2(w0[t], w1[t]);
                    else
                        stage_u[(size_t)(part[t]-NPART)*STAGE_CAP + pos] = make_uint2(w0[t], w1[t]);
                }
            }
        }
    }
}

// ---------------------------------------------------------------------------
// Build pass 2 (fused e+u): partition = blockIdx%8 (XCD affinity). 4 items
// per thread via 2x uint4 (4 parallel atomic chains); e-chunks and u-chunks
// in one launch so each type's tail is filled by the other.
// ---------------------------------------------------------------------------
__global__ __launch_bounds__(256) void scatter_kernel(const uint2* __restrict__ stage_e,
                                                      const uint2* __restrict__ stage_u,
                                                      const int* __restrict__ cursor,
                                                      int* __restrict__ cnt_e,
                                                      int* __restrict__ cnt_u,
                                                      int* __restrict__ sorted_e,
                                                      unsigned* __restrict__ sorted_u) {
    const int part = blockIdx.x & (NPART-1);
    const int cid  = blockIdx.x >> 3;          // 0..2*NCH-1
    const bool isE = cid < NCH;
    const int chunk = isE ? cid : cid - NCH;
    const int n = min(cursor[(isE ? part : NPART + part)*CSTRIDE], STAGE_CAP);
    const uint2* s = (isE ? stage_e : stage_u) + (size_t)part*STAGE_CAP;
    int* cnt = isE ? cnt_e : cnt_u;

    const int i0 = (chunk*256 + threadIdx.x) * 4;
    if (i0 >= n) return;
    const bool h1 = i0 + 1 < n, h2 = i0 + 2 < n, h3 = i0 + 3 < n;
    uint4 a = *(const uint4*)(s + i0);         // 16B aligned (i0 multiple of 4)
    uint4 b;
    if (h2) b = *(const uint4*)(s + i0 + 2);
    int pos0 = atomicAdd(&cnt[a.x], 1);
    int pos1 = h1 ? atomicAdd(&cnt[a.z], 1) : 0;
    int pos2 = h2 ? atomicAdd(&cnt[b.x], 1) : 0;
    int pos3 = h3 ? atomicAdd(&cnt[b.z], 1) : 0;
    if (isE) {
        if (pos0 < SLOT)       sorted_e[(size_t)a.x*SLOT + pos0] = (int)a.y;
        if (h1 && pos1 < SLOT) sorted_e[(size_t)a.z*SLOT + pos1] = (int)a.w;
        if (h2 && pos2 < SLOT) sorted_e[(size_t)b.x*SLOT + pos2] = (int)b.y;
        if (h3 && pos3 < SLOT) sorted_e[(size_t)b.z*SLOT + pos3] = (int)b.w;
    } else {
        if (pos0 < SLOT)       sorted_u[(size_t)a.x*SLOT + pos0] = a.y;
        if (h1 && pos1 < SLOT) sorted_u[(size_t)a.z*SLOT + pos1] = a.w;
        if (h2 && pos2 < SLOT) sorted_u[(size_t)b.x*SLOT + pos2] = b.y;
        if (h3 && pos3 < SLOT) sorted_u[(size_t)b.z*SLOT + pos3] = b.w;
    }
}

// ---------------------------------------------------------------------------
// FUSED per-hop gather, TWO ROWS PER WAVE (round-6 verified config: VGPR 36,
// occ ~67%, ~3.45 TB/s -- the 4-row variant collapsed occupancy, reverted).
// Blocks [0, EBLOCKS) entity, rest user. Bit-identical accumulation order.
// ---------------------------------------------------------------------------
__global__ __launch_bounds__(256) void gather_eu_kernel(const __half2* __restrict__ e_tab,
                                                        const int* __restrict__ cnt_e,
                                                        const int* __restrict__ sorted_e,
                                                        const float* __restrict__ r_emb,
                                                        const float2* __restrict__ base_e,
                                                        float2* __restrict__ res_e,
                                                        __half2* __restrict__ e_out,
                                                        const int* __restrict__ cnt_u,
                                                        const unsigned* __restrict__ sorted_u,
                                                        const float2* __restrict__ u_prev,
                                                        const float* __restrict__ i2,
                                                        const float2* __restrict__ base_u,
                                                        float2* __restrict__ res_u,
                                                        float2* __restrict__ u_out,
                                                        int store, int write_res) {
    __shared__ float2 s_i2[N_INT*64];
    __shared__ float  tr[4][2][132];

    const int wv   = threadIdx.x >> 6;
    const int lane = threadIdx.x & 63;
    const int g = lane >> 4, sl = lane & 15;
    const float4* e4 = (const float4*)e_tab;   // row stride = 16 float4

    if (blockIdx.x < EBLOCKS) {
        // ================= ENTITY GATHER (no LDS, no barrier) ==============
        const int row0 = blockIdx.x*8 + wv*2;
        const int row1 = row0 + 1;
        const int deg0 = min(cnt_e[row0], SLOT);
        const int deg1 = min(cnt_e[row1], SLOT);
        int p0 = (lane < deg0) ? sorted_e[(size_t)row0*SLOT + lane] : 0;
        int p1 = (lane < deg1) ? sorted_e[(size_t)row1*SLOT + lane] : 0;

        const float4* r4 = (const float4*)r_emb;  // row stride = 32 float4
        float accA[8] = {0,0,0,0,0,0,0,0};
        float accB[8] = {0,0,0,0,0,0,0,0};

#define EFMA(ACC, RAW, PM) do { \
            F4H8 u_; u_.f4 = (RAW); \
            const __half* h_ = (const __half*)u_.h2; \
            const int rr_ = (PM) >> 20; \
            float4 w0_ = r4[rr_*32 + sl*2]; \
            float4 w1_ = r4[rr_*32 + sl*2 + 1]; \
            ACC[0] += __half2float(h_[0]) * w0_.x; \
            ACC[1] += __half2float(h_[1]) * w0_.y; \
            ACC[2] += __half2float(h_[2]) * w0_.z; \
            ACC[3] += __half2float(h_[3]) * w0_.w; \
            ACC[4] += __half2float(h_[4]) * w1_.x; \
            ACC[5] += __half2float(h_[5]) * w1_.y; \
            ACC[6] += __half2float(h_[6]) * w1_.z; \
            ACC[7] += __half2float(h_[7]) * w1_.w; \
        } while (0)

        const int dm = max(deg0, deg1);
        for (int k = 0; k < dm; k += 8) {
            const int meA = k + g, meB = k + 4 + g;
            const int pm00 = __shfl(p0, meA), pm01 = __shfl(p0, meB);
            const int pm10 = __shfl(p1, meA), pm11 = __shfl(p1, meB);
            const bool a00 = meA < deg0, a01 = meB < deg0;
            const bool a10 = meA < deg1, a11 = meB < deg1;
            float4 r00, r01, r10, r11;
            if (a00) r00 = e4[(size_t)(pm00 & 0xFFFFF)*16 + sl];
            if (a01) r01 = e4[(size_t)(pm01 & 0xFFFFF)*16 + sl];
            if (a10) r10 = e4[(size_t)(pm10 & 0xFFFFF)*16 + sl];
            if (a11) r11 = e4[(size_t)(pm11 & 0xFFFFF)*16 + sl];
            if (a00) EFMA(accA, r00, pm00);
            if (a01) EFMA(accA, r01, pm01);
            if (a10) EFMA(accB, r10, pm10);
            if (a11) EFMA(accB, r11, pm11);
        }
#undef EFMA

        #pragma unroll
        for (int j = 0; j < 8; ++j) {
            accA[j] += __shfl_xor(accA[j], 16);
            accA[j] += __shfl_xor(accA[j], 32);
            accB[j] += __shfl_xor(accB[j], 16);
            accB[j] += __shfl_xor(accB[j], 32);
        }
        const float invA = (deg0 > 0) ? 1.0f/(float)deg0 : 0.0f;
        const float invB = (deg1 > 0) ? 1.0f/(float)deg1 : 0.0f;
        float ssA = 0.f, ssB = 0.f;
        #pragma unroll
        for (int j = 0; j < 8; ++j) {
            accA[j] *= invA; ssA += accA[j]*accA[j];
            accB[j] *= invB; ssB += accB[j]*accB[j];
        }
        #pragma unroll
        for (int o = 8; o > 0; o >>= 1) {   // within 16-lane group
            ssA += __shfl_xor(ssA, o);
            ssB += __shfl_xor(ssB, o);
        }
        const float invnA = 1.0f / fmaxf(sqrtf(ssA), 1e-12f);
        const float invnB = 1.0f / fmaxf(sqrtf(ssB), 1e-12f);
        #pragma unroll
        for (int j = 0; j < 8; ++j) { accA[j] *= invnA; accB[j] *= invnB; }

#define EPI(ROW, ACC) do { \
            size_t r16 = (size_t)(ROW)*16 + sl; \
            if (store) { \
                F4H8 u_; \
                u_.h2[0] = __floats2half2_rn(ACC[0], ACC[1]); \
                u_.h2[1] = __floats2half2_rn(ACC[2], ACC[3]); \
                u_.h2[2] = __floats2half2_rn(ACC[4], ACC[5]); \
                u_.h2[3] = __floats2half2_rn(ACC[6], ACC[7]); \
                ((float4*)e_out)[r16] = u_.f4; \
            } \
            if (write_res) { \
                F4H8 pv; pv.f4 = ((const float4*)e_tab)[r16]; \
                const float4* b4 = (const float4*)base_e; \
                float4 ba = b4[(size_t)(ROW)*32 + sl*2]; \
                float4 bb = b4[(size_t)(ROW)*32 + sl*2 + 1]; \
                float2 q0 = __half22float2(pv.h2[0]); \
                float2 q1 = __half22float2(pv.h2[1]); \
                float2 q2 = __half22float2(pv.h2[2]); \
                float2 q3 = __half22float2(pv.h2[3]); \
                float4 ra = make_float4(ba.x + q0.x + ACC[0], ba.y + q0.y + ACC[1], \
                                        ba.z + q1.x + ACC[2], ba.w + q1.y + ACC[3]); \
                float4 rb = make_float4(bb.x + q2.x + ACC[4], bb.y + q2.y + ACC[5], \
                                        bb.z + q3.x + ACC[6], bb.w + q3.y + ACC[7]); \
                ((float4*)res_e)[(size_t)(ROW)*32 + sl*2]     = ra; \
                ((float4*)res_e)[(size_t)(ROW)*32 + sl*2 + 1] = rb; \
            } \
        } while (0)

        if (g == 0)      EPI(row0, accA);
        else if (g == 1) EPI(row1, accB);
#undef EPI
    } else {
        // ================= USER GATHER =====================================
        for (int k = threadIdx.x; k < N_INT*64; k += 256) s_i2[k] = ((const float2*)i2)[k];
        __syncthreads();
        const int ub = blockIdx.x - EBLOCKS;
        const int row0 = ub*8 + wv*2;
        const int row1 = row0 + 1;
        const int deg0 = min(cnt_u[row0], SLOT);
        const int deg1 = min(cnt_u[row1], SLOT);
        unsigned p0 = (lane < deg0) ? sorted_u[(size_t)row0*SLOT + lane] : 0u;
        unsigned p1 = (lane < deg1) ? sorted_u[(size_t)row1*SLOT + lane] : 0u;

        const float qs = 1.0f/32767.0f;
        float accA[8] = {0,0,0,0,0,0,0,0};
        float accB[8] = {0,0,0,0,0,0,0,0};

#define UFMA(ACC, RAW, Q) do { \
            F4H8 u_; u_.f4 = (RAW); \
            const __half* h_ = (const __half*)u_.h2; \
            const float v_ = (float)((Q) >> 17) * qs; \
            ACC[0] += v_ * __half2float(h_[0]); \
            ACC[1] += v_ * __half2float(h_[1]); \
            ACC[2] += v_ * __half2float(h_[2]); \
            ACC[3] += v_ * __half2float(h_[3]); \
            ACC[4] += v_ * __half2float(h_[4]); \
            ACC[5] += v_ * __half2float(h_[5]); \
            ACC[6] += v_ * __half2float(h_[6]); \
            ACC[7] += v_ * __half2float(h_[7]); \
        } while (0)

        const int dm = max(deg0, deg1);
        for (int k = 0; k < dm; k += 8) {
            const int meA = k + g, meB = k + 4 + g;
            const unsigned q00 = __shfl(p0, meA), q01 = __shfl(p0, meB);
            const unsigned q10 = __shfl(p1, meA), q11 = __shfl(p1, meB);
            const bool a00 = meA < deg0, a01 = meB < deg0;
            const bool a10 = meA < deg1, a11 = meB < deg1;
            float4 r00, r01, r10, r11;
            if (a00) r00 = e4[(size_t)(q00 & 0x1FFFFu)*16 + sl];
            if (a01) r01 = e4[(size_t)(q01 & 0x1FFFFu)*16 + sl];
            if (a10) r10 = e4[(size_t)(q10 & 0x1FFFFu)*16 + sl];
            if (a11) r11 = e4[(size_t)(q11 & 0x1FFFFu)*16 + sl];
            if (a00) UFMA(accA, r00, q00);
            if (a01) UFMA(accA, r01, q01);
            if (a10) UFMA(accB, r10, q10);
            if (a11) UFMA(accB, r11, q11);
        }
#undef UFMA

        #pragma unroll
        for (int j = 0; j < 8; ++j) {
            accA[j] += __shfl_xor(accA[j], 16);
            accA[j] += __shfl_xor(accA[j], 32);
            accB[j] += __shfl_xor(accB[j], 16);
            accB[j] += __shfl_xor(accB[j], 32);
        }
        // transpose: sl-layout (16 lanes x 8 dims) -> float2 layout (64 x 2)
        if (g == 0) {
            #pragma unroll
            for (int j = 0; j < 8; ++j) tr[wv][0][sl*8 + j] = accA[j];
        } else if (g == 1) {
            #pragma unroll
            for (int j = 0; j < 8; ++j) tr[wv][1][sl*8 + j] = accB[j];
        }
        __syncthreads();
        const float s00 = tr[wv][0][2*lane], s01 = tr[wv][0][2*lane + 1];
        const float s10 = tr[wv][1][2*lane], s11 = tr[wv][1][2*lane + 1];

        const size_t o0 = (size_t)row0*64 + lane;
        const size_t o1 = (size_t)row1*64 + lane;
        const float2 up0 = u_prev[o0];
        const float2 up1 = u_prev[o1];
        float dot0[N_INT], dot1[N_INT];
        #pragma unroll
        for (int i = 0; i < N_INT; ++i) {
            float2 w = s_i2[i*64 + lane];
            float pr0 = up0.x*w.x + up0.y*w.y;
            float pr1 = up1.x*w.x + up1.y*w.y;
            #pragma unroll
            for (int o = 32; o > 0; o >>= 1) {
                pr0 += __shfl_xor(pr0, o);
                pr1 += __shfl_xor(pr1, o);
            }
            dot0[i] = pr0; dot1[i] = pr1;
        }
        float m0 = dot0[0], m1 = dot1[0];
        #pragma unroll
        for (int i = 1; i < N_INT; ++i) { m0 = fmaxf(m0, dot0[i]); m1 = fmaxf(m1, dot1[i]); }
        float sm0 = 0.f, sm1 = 0.f;
        #pragma unroll
        for (int i = 0; i < N_INT; ++i) {
            dot0[i] = expf(dot0[i] - m0); sm0 += dot0[i];
            dot1[i] = expf(dot1[i] - m1); sm1 += dot1[i];
        }
        float f00 = 0.f, f01 = 0.f, f10 = 0.f, f11 = 0.f;
        #pragma unroll
        for (int i = 0; i < N_INT; ++i) {
            float a0 = dot0[i] / sm0;
            float a1 = dot1[i] / sm1;
            float2 w = s_i2[i*64 + lane];
            f00 += a0*w.x; f01 += a0*w.y;
            f10 += a1*w.x; f11 += a1*w.y;
        }
        float x00 = s00 * (1.0f + f00), x01 = s01 * (1.0f + f01);
        float x10 = s10 * (1.0f + f10), x11 = s11 * (1.0f + f11);
        float ss0 = x00*x00 + x01*x01;
        float ss1 = x10*x10 + x11*x11;
        #pragma unroll
        for (int o = 32; o > 0; o >>= 1) {
            ss0 += __shfl_xor(ss0, o);
            ss1 += __shfl_xor(ss1, o);
        }
        const float invn0 = 1.0f / fmaxf(sqrtf(ss0), 1e-12f);
        const float invn1 = 1.0f / fmaxf(sqrtf(ss1), 1e-12f);
        x00 *= invn0; x01 *= invn0;
        x10 *= invn1; x11 *= invn1;
        if (store) {
            u_out[o0] = make_float2(x00, x01);
            u_out[o1] = make_float2(x10, x11);
        }
        if (write_res) {
            float2 b0 = base_u[o0];
            float2 b1 = base_u[o1];
            res_u[o0] = make_float2(b0.x + up0.x + x00, b0.y + up0.y + x01);
            res_u[o1] = make_float2(b1.x + up1.x + x10, b1.y + up1.y + x11);
        }
    }
}

// ---------------------------------------------------------------------------
extern "C" void kernel_launch(void* const* d_in, const int* in_sizes, int n_in,
                              void* d_out, int out_size, void* d_ws, size_t ws_size,
                              hipStream_t stream) {
    const float* user_emb   = (const float*)d_in[0];
    const float* entity_emb = (const float*)d_in[1];
    const float* intent_emb = (const float*)d_in[2];
    const int*   edge_index = (const int*)  d_in[3];
    const int*   edge_type  = (const int*)  d_in[4];
    const int*   irows      = (const int*)  d_in[5];
    const int*   icols      = (const int*)  d_in[6];
    const float* ivals      = (const float*)d_in[7];
    const float* r_emb      = (const float*)d_in[8];

    float* out     = (float*)d_out;
    float* res_e   = out;
    float* res_u   = out + (size_t)N_ENT*EMB;
    float* out_cor = out + (size_t)N_ENT*EMB + (size_t)N_USERS*EMB;

    const int* head = edge_index;
    const int* tail = edge_index + N_EDGES;

    char* ws = (char*)d_ws;
    __half2* entF16 = (__half2*)ws;  ws += (size_t)N_ENT*EMB*2;
    __half2* eA     = (__half2*)ws;  ws += (size_t)N_ENT*EMB*2;
    float2*  uA     = (float2*)ws;   ws += (size_t)N_USERS*EMB*4;
    int*     sorted_e = (int*)ws;    ws += (size_t)N_ENT*SLOT*4;
    unsigned* sorted_u = (unsigned*)ws; ws += (size_t)N_USERS*SLOT*4;
    // ---- contiguous zero-region: one memset covers cnt_e|cnt_u|cursor|done
    char* zbase = ws;
    int* cnt_e = (int*)ws;           ws += (size_t)N_ENT*4;
    int* cnt_u = (int*)ws;           ws += (size_t)N_USERS*4;
    int* cursor = (int*)ws;          ws += 2*NPART*CSTRIDE*4;
    int* done   = (int*)ws;          ws += 128;
    size_t zbytes = (size_t)(ws - zbase);
    // ----
    float* i2  = (float*)ws;         ws += N_INT*EMB*4;
    float* ws_cor = (float*)ws;      ws += 16*4;

    // staging aliases eA/uA: both are dead until gather hop 1 writes them,
    // and the scatter kernel (the consumer) completes before that on stream.
    uint2* stage_e = (uint2*)eA;     // 8 MB <= 25.6 MB region
    uint2* stage_u = (uint2*)uA;     // 8 MB <= 25.6 MB region

    hipMemsetAsync(zbase, 0, zbytes, stream);

    // one mega-launch: cor(10) + intent2(5) + conv(3125) + stage(2048)
    misc_kernel<<<MISCGRID, 256, 0, stream>>>(intent_emb, r_emb, i2,
                                              ws_cor, out_cor, done,
                                              (const float2*)entity_emb, entF16,
                                              head, tail, edge_type,
                                              irows, icols, ivals,
                                              cursor, stage_e, stage_u);

    // fused e+u scatter, 4 items/thread (4 parallel atomic chains)
    scatter_kernel<<<NPART*2*NCH, 256, 0, stream>>>(stage_e, stage_u, cursor,
                                                    cnt_e, cnt_u, sorted_e, sorted_u);

    const float2* ent2 = (const float2*)entity_emb;
    const float2* usr2 = (const float2*)user_emb;

    // hop 1 (fused e+u): store eA(f16)/uA(f32), no residual traffic
    gather_eu_kernel<<<EBLOCKS + UBLOCKS, 256, 0, stream>>>(
        entF16, cnt_e, sorted_e, r_emb, ent2, (float2*)res_e, eA,
        cnt_u, sorted_u, usr2, i2, usr2, (float2*)res_u, uA, 1, 0);

    // hop 2 (fused e+u): res = base + prev + x
    gather_eu_kernel<<<EBLOCKS + UBLOCKS, 256, 0, stream>>>(
        eA, cnt_e, sorted_e, r_emb, ent2, (float2*)res_e, eA,
        cnt_u, sorted_u, (const float2*)uA, i2, usr2, (float2*)res_u, uA, 0, 1);
}

// Round 9
// 439.462 us; speedup vs baseline: 1.2192x; 1.0235x over previous
//
#include <hip/hip_runtime.h>
#include <hip/hip_fp16.h>
#include <math.h>

#define N_USERS 50000
#define N_ENT   100000
#define N_INT   5
#define EMB     128
#define N_REL   20
#define N_EDGES 1000000
#define NNZ     1000000
#define SLOT    64   // max degree; Poisson(10)/Poisson(20) => P(>64) ~ 1e-30
#define SITEMS  4    // items per thread in build portion
#define EBLOCKS (N_ENT/8)    // 12500 entity-gather blocks (2 rows/wave x 4 waves)
#define UBLOCKS (N_USERS/8)  // 6250 user-gather blocks

// misc_kernel block ranges: cor | intent2 | BUILD (early: latency-bound,
// overlaps with conv's BW-bound streaming) | conv
#define CORB    10                 // cor pair blocks
#define I2END   (CORB + N_INT)     // 15
#define BLDBLK  2048               // build blocks: 2048*1024 items >= 2M
#define BLDEND  (I2END + BLDBLK)   // 2063
#define CONVBLK 3125               // conv blocks: 3125*2048 float2 = 6.4M exactly
#define MISCGRID (BLDEND + CONVBLK)  // 5188

union F4H8 { float4 f4; __half2 h2[4]; };

// ---------------------------------------------------------------------------
// MISC mega-kernel: cor pairs (+last-block sum), intent2, single-pass direct
// bucket build (1x coalesced scan + memory-side atomics + random stores --
// replaces the 2-pass stage+scatter: same atomics/stores, minus the 32MB
// staging round-trip and one dispatch), and f32->f16 conv.
// ---------------------------------------------------------------------------
__global__ __launch_bounds__(256) void misc_kernel(const float* __restrict__ intent,
                                                   const float* __restrict__ r_emb,
                                                   float* __restrict__ i2,
                                                   float* __restrict__ partial,
                                                   float* __restrict__ out_cor,
                                                   int* __restrict__ done,
                                                   const float2* __restrict__ conv_in,
                                                   __half2* __restrict__ conv_out,
                                                   const int* __restrict__ head,
                                                   const int* __restrict__ tail,
                                                   const int* __restrict__ etype,
                                                   const int* __restrict__ irows,
                                                   const int* __restrict__ icols,
                                                   const float* __restrict__ ivals,
                                                   int* __restrict__ cnt_e,
                                                   int* __restrict__ cnt_u,
                                                   int* __restrict__ sorted_e,
                                                   unsigned* __restrict__ sorted_u) {
    __shared__ float t1[EMB], t2[EMB], rma[EMB], rmb[EMB];
    __shared__ float red[256];
    __shared__ float sh_mean_a, sh_mean_b;
    __shared__ float dotsh[N_REL];
    const int tid = threadIdx.x;

    if (blockIdx.x < CORB) {
        // ================= COR PAIR (10 blocks) ============================
        const int p = blockIdx.x;
        const int pi[10] = {0,0,0,0,1,1,1,2,2,3};
        const int pj[10] = {1,2,3,4,2,3,4,3,4,4};

        if (tid < EMB) {
            t1[tid] = intent[pi[p]*EMB + tid];
            t2[tid] = intent[pj[p]*EMB + tid];
        }
        __syncthreads();
        if (tid < EMB) {
            float x1 = t1[tid], x2 = t2[tid];
            float sa = 0.f, sb = 0.f;
            for (int k = 0; k < EMB; ++k) {
                float da = x1 - t1[k];
                float db = x2 - t2[k];
                sa += sqrtf(da*da + 1e-8f);
                sb += sqrtf(db*db + 1e-8f);
            }
            rma[tid] = sa / (float)EMB;
            rmb[tid] = sb / (float)EMB;
        }
        __syncthreads();
        red[tid] = (tid < EMB) ? rma[tid] : 0.f;
        __syncthreads();
        for (int s = 128; s > 0; s >>= 1) { if (tid < s) red[tid] += red[tid+s]; __syncthreads(); }
        if (tid == 0) sh_mean_a = red[0] / (float)EMB;
        __syncthreads();
        red[tid] = (tid < EMB) ? rmb[tid] : 0.f;
        __syncthreads();
        for (int s = 128; s > 0; s >>= 1) { if (tid < s) red[tid] += red[tid+s]; __syncthreads(); }
        if (tid == 0) sh_mean_b = red[0] / (float)EMB;
        __syncthreads();
        const float mean_a = sh_mean_a, mean_b = sh_mean_b;

        float lab = 0.f, laa = 0.f, lbb = 0.f;
        for (int idx = tid; idx < EMB*EMB; idx += 256) {
            int r = idx >> 7, c = idx & (EMB-1);
            float da = t1[r] - t1[c];
            float db = t2[r] - t2[c];
            float av = sqrtf(da*da + 1e-8f);
            float bv = sqrtf(db*db + 1e-8f);
            float A = av - rma[r] - rma[c] + mean_a;
            float B = bv - rmb[r] - rmb[c] + mean_b;
            lab += A*B; laa += A*A; lbb += B*B;
        }
        red[tid] = lab; __syncthreads();
        for (int s = 128; s > 0; s >>= 1) { if (tid < s) red[tid] += red[tid+s]; __syncthreads(); }
        float sab = red[0]; __syncthreads();
        red[tid] = laa; __syncthreads();
        for (int s = 128; s > 0; s >>= 1) { if (tid < s) red[tid] += red[tid+s]; __syncthreads(); }
        float saa = red[0]; __syncthreads();
        red[tid] = lbb; __syncthreads();
        for (int s = 128; s > 0; s >>= 1) { if (tid < s) red[tid] += red[tid+s]; __syncthreads(); }
        float sbb = red[0]; __syncthreads();

        if (tid == 0) {
            const float d2 = (float)(EMB*EMB);
            float dab = sqrtf(fmaxf(sab/d2, 0.f) + 1e-8f);
            float daa = sqrtf(fmaxf(saa/d2, 0.f) + 1e-8f);
            float dbb = sqrtf(fmaxf(sbb/d2, 0.f) + 1e-8f);
            partial[p] = dab / sqrtf(daa*dbb + 1e-8f);
            __threadfence();
            int t = atomicAdd(done, 1);
            if (t == CORB - 1) {   // last cor block sums (fences + device atomics)
                float s = 0.f;
                volatile float* vp = (volatile float*)partial;
                for (int i = 0; i < CORB; ++i) s += vp[i];
                out_cor[0] = s;
            }
        }
    } else if (blockIdx.x < I2END) {
        // ================= INTENT2 (5 blocks, 256 thr, d<128 active) =======
        const int i = blockIdx.x - CORB;
        const int d = tid;
        int start, n;
        if      (i == 0) { start = 0;  n = 20; }
        else if (i == 1) { start = 0;  n = 4;  }
        else if (i == 2) { start = 4;  n = 4;  }
        else if (i == 3) { start = 8;  n = 4;  }
        else             { start = 12; n = 8;  }

        const float v = (d < EMB) ? intent[i*EMB + d] : 0.f;
        for (int j = 0; j < n; ++j) {
            if (d < EMB) red[d] = v * r_emb[(start+j)*EMB + d];
            __syncthreads();
            for (int s = 64; s > 0; s >>= 1) { if (d < s) red[d] += red[d+s]; __syncthreads(); }
            if (d == 0) dotsh[j] = red[0];
            __syncthreads();
        }
        if (d < EMB) {
            float m = -1e30f;
            for (int j = 0; j < n; ++j) m = fmaxf(m, dotsh[j]);
            float s = 0.f;
            float att[N_REL];
            for (int j = 0; j < n; ++j) { att[j] = expf(dotsh[j] - m); s += att[j]; }
            float out = 0.f;
            for (int j = 0; j < n; ++j) out += (att[j]/s) * r_emb[(start+j)*EMB + d];
            out /= (float)n;
            i2[i*EMB + d] = 0.5f * (out + v);
        }
    } else if (blockIdx.x < BLDEND) {
        // ================= DIRECT BUILD (2048 blocks x 1024 items) =========
        // 1x coalesced scan; 4 independent atomic chains per thread; stores
        // are fire-and-forget. Scheduled before conv so the atomic latency
        // overlaps conv's streaming.
        const int TOTAL = N_EDGES + NNZ;
        const int base = (blockIdx.x - I2END) * (256*SITEMS);

        int rows[SITEMS]; unsigned words[SITEMS];
        bool act[SITEMS], isE[SITEMS];
        #pragma unroll
        for (int t = 0; t < SITEMS; ++t) {
            const int i = base + t*256 + tid;   // coalesced per sub-step
            act[t] = i < TOTAL;
            isE[t] = i < N_EDGES;
            if (act[t]) {
                if (isE[t]) {
                    rows[t]  = head[i];
                    words[t] = (unsigned)(tail[i] | ((etype[i]-1) << 20));
                } else {
                    int j = i - N_EDGES;
                    rows[t]  = irows[j];
                    unsigned q = (unsigned)(ivals[j]*32767.0f + 0.5f);
                    words[t] = (q << 17) | (unsigned)icols[j];
                }
            }
        }
        int pos[SITEMS];
        #pragma unroll
        for (int t = 0; t < SITEMS; ++t)
            if (act[t]) pos[t] = atomicAdd(isE[t] ? &cnt_e[rows[t]] : &cnt_u[rows[t]], 1);
        #pragma unroll
        for (int t = 0; t < SITEMS; ++t) {
            if (act[t] && pos[t] < SLOT) {
                if (isE[t]) sorted_e[(size_t)rows[t]*SLOT + pos[t]] = (int)words[t];
                else        sorted_u[(size_t)rows[t]*SLOT + pos[t]] = words[t];
            }
        }
    } else {
        // ================= CONV f32->f16 (3125 blocks x 2048 float2) =======
        const int base = (blockIdx.x - BLDEND) * 2048;
        #pragma unroll
        for (int t = 0; t < 8; ++t) {
            int idx = base + t*256 + tid;
            float2 v = conv_in[idx];
            conv_out[idx] = __floats2half2_rn(v.x, v.y);
        }
    }
}

// ---------------------------------------------------------------------------
// FUSED per-hop gather, TWO ROWS PER WAVE (verified config: VGPR 36, occ
// ~67%, ~3.45 TB/s = apparent random-256B pattern ceiling; 4-row variant
// collapsed occupancy -- do not revisit). Blocks [0, EBLOCKS) entity, rest
// user. Bit-identical accumulation order vs earlier verified versions.
// ---------------------------------------------------------------------------
__global__ __launch_bounds__(256) void gather_eu_kernel(const __half2* __restrict__ e_tab,
                                                        const int* __restrict__ cnt_e,
                                                        const int* __restrict__ sorted_e,
                                                        const float* __restrict__ r_emb,
                                                        const float2* __restrict__ base_e,
                                                        float2* __restrict__ res_e,
                                                        __half2* __restrict__ e_out,
                                                        const int* __restrict__ cnt_u,
                                                        const unsigned* __restrict__ sorted_u,
                                                        const float2* __restrict__ u_prev,
                                                        const float* __restrict__ i2,
                                                        const float2* __restrict__ base_u,
                                                        float2* __restrict__ res_u,
                                                        float2* __restrict__ u_out,
                                                        int store, int write_res) {
    __shared__ float2 s_i2[N_INT*64];
    __shared__ float  tr[4][2][132];

    const int wv   = threadIdx.x >> 6;
    const int lane = threadIdx.x & 63;
    const int g = lane >> 4, sl = lane & 15;
    const float4* e4 = (const float4*)e_tab;   // row stride = 16 float4

    if (blockIdx.x < EBLOCKS) {
        // ================= ENTITY GATHER (no LDS, no barrier) ==============
        const int row0 = blockIdx.x*8 + wv*2;
        const int row1 = row0 + 1;
        const int deg0 = min(cnt_e[row0], SLOT);
        const int deg1 = min(cnt_e[row1], SLOT);
        int p0 = (lane < deg0) ? sorted_e[(size_t)row0*SLOT + lane] : 0;
        int p1 = (lane < deg1) ? sorted_e[(size_t)row1*SLOT + lane] : 0;

        const float4* r4 = (const float4*)r_emb;  // row stride = 32 float4
        float accA[8] = {0,0,0,0,0,0,0,0};
        float accB[8] = {0,0,0,0,0,0,0,0};

#define EFMA(ACC, RAW, PM) do { \
            F4H8 u_; u_.f4 = (RAW); \
            const __half* h_ = (const __half*)u_.h2; \
            const int rr_ = (PM) >> 20; \
            float4 w0_ = r4[rr_*32 + sl*2]; \
            float4 w1_ = r4[rr_*32 + sl*2 + 1]; \
            ACC[0] += __half2float(h_[0]) * w0_.x; \
            ACC[1] += __half2float(h_[1]) * w0_.y; \
            ACC[2] += __half2float(h_[2]) * w0_.z; \
            ACC[3] += __half2float(h_[3]) * w0_.w; \
            ACC[4] += __half2float(h_[4]) * w1_.x; \
            ACC[5] += __half2float(h_[5]) * w1_.y; \
            ACC[6] += __half2float(h_[6]) * w1_.z; \
            ACC[7] += __half2float(h_[7]) * w1_.w; \
        } while (0)

        const int dm = max(deg0, deg1);
        for (int k = 0; k < dm; k += 8) {
            const int meA = k + g, meB = k + 4 + g;
            const int pm00 = __shfl(p0, meA), pm01 = __shfl(p0, meB);
            const int pm10 = __shfl(p1, meA), pm11 = __shfl(p1, meB);
            const bool a00 = meA < deg0, a01 = meB < deg0;
            const bool a10 = meA < deg1, a11 = meB < deg1;
            float4 r00, r01, r10, r11;
            if (a00) r00 = e4[(size_t)(pm00 & 0xFFFFF)*16 + sl];
            if (a01) r01 = e4[(size_t)(pm01 & 0xFFFFF)*16 + sl];
            if (a10) r10 = e4[(size_t)(pm10 & 0xFFFFF)*16 + sl];
            if (a11) r11 = e4[(size_t)(pm11 & 0xFFFFF)*16 + sl];
            if (a00) EFMA(accA, r00, pm00);
            if (a01) EFMA(accA, r01, pm01);
            if (a10) EFMA(accB, r10, pm10);
            if (a11) EFMA(accB, r11, pm11);
        }
#undef EFMA

        #pragma unroll
        for (int j = 0; j < 8; ++j) {
            accA[j] += __shfl_xor(accA[j], 16);
            accA[j] += __shfl_xor(accA[j], 32);
            accB[j] += __shfl_xor(accB[j], 16);
            accB[j] += __shfl_xor(accB[j], 32);
        }
        const float invA = (deg0 > 0) ? 1.0f/(float)deg0 : 0.0f;
        const float invB = (deg1 > 0) ? 1.0f/(float)deg1 : 0.0f;
        float ssA = 0.f, ssB = 0.f;
        #pragma unroll
        for (int j = 0; j < 8; ++j) {
            accA[j] *= invA; ssA += accA[j]*accA[j];
            accB[j] *= invB; ssB += accB[j]*accB[j];
        }
        #pragma unroll
        for (int o = 8; o > 0; o >>= 1) {   // within 16-lane group
            ssA += __shfl_xor(ssA, o);
            ssB += __shfl_xor(ssB, o);
        }
        const float invnA = 1.0f / fmaxf(sqrtf(ssA), 1e-12f);
        const float invnB = 1.0f / fmaxf(sqrtf(ssB), 1e-12f);
        #pragma unroll
        for (int j = 0; j < 8; ++j) { accA[j] *= invnA; accB[j] *= invnB; }

#define EPI(ROW, ACC) do { \
            size_t r16 = (size_t)(ROW)*16 + sl; \
            if (store) { \
                F4H8 u_; \
                u_.h2[0] = __floats2half2_rn(ACC[0], ACC[1]); \
                u_.h2[1] = __floats2half2_rn(ACC[2], ACC[3]); \
                u_.h2[2] = __floats2half2_rn(ACC[4], ACC[5]); \
                u_.h2[3] = __floats2half2_rn(ACC[6], ACC[7]); \
                ((float4*)e_out)[r16] = u_.f4; \
            } \
            if (write_res) { \
                F4H8 pv; pv.f4 = ((const float4*)e_tab)[r16]; \
                const float4* b4 = (const float4*)base_e; \
                float4 ba = b4[(size_t)(ROW)*32 + sl*2]; \
                float4 bb = b4[(size_t)(ROW)*32 + sl*2 + 1]; \
                float2 q0 = __half22float2(pv.h2[0]); \
                float2 q1 = __half22float2(pv.h2[1]); \
                float2 q2 = __half22float2(pv.h2[2]); \
                float2 q3 = __half22float2(pv.h2[3]); \
                float4 ra = make_float4(ba.x + q0.x + ACC[0], ba.y + q0.y + ACC[1], \
                                        ba.z + q1.x + ACC[2], ba.w + q1.y + ACC[3]); \
                float4 rb = make_float4(bb.x + q2.x + ACC[4], bb.y + q2.y + ACC[5], \
                                        bb.z + q3.x + ACC[6], bb.w + q3.y + ACC[7]); \
                ((float4*)res_e)[(size_t)(ROW)*32 + sl*2]     = ra; \
                ((float4*)res_e)[(size_t)(ROW)*32 + sl*2 + 1] = rb; \
            } \
        } while (0)

        if (g == 0)      EPI(row0, accA);
        else if (g == 1) EPI(row1, accB);
#undef EPI
    } else {
        // ================= USER GATHER =====================================
        for (int k = threadIdx.x; k < N_INT*64; k += 256) s_i2[k] = ((const float2*)i2)[k];
        __syncthreads();
        const int ub = blockIdx.x - EBLOCKS;
        const int row0 = ub*8 + wv*2;
        const int row1 = row0 + 1;
        const int deg0 = min(cnt_u[row0], SLOT);
        const int deg1 = min(cnt_u[row1], SLOT);
        unsigned p0 = (lane < deg0) ? sorted_u[(size_t)row0*SLOT + lane] : 0u;
        unsigned p1 = (lane < deg1) ? sorted_u[(size_t)row1*SLOT + lane] : 0u;

        const float qs = 1.0f/32767.0f;
        float accA[8] = {0,0,0,0,0,0,0,0};
        float accB[8] = {0,0,0,0,0,0,0,0};

#define UFMA(ACC, RAW, Q) do { \
            F4H8 u_; u_.f4 = (RAW); \
            const __half* h_ = (const __half*)u_.h2; \
            const float v_ = (float)((Q) >> 17) * qs; \
            ACC[0] += v_ * __half2float(h_[0]); \
            ACC[1] += v_ * __half2float(h_[1]); \
            ACC[2] += v_ * __half2float(h_[2]); \
            ACC[3] += v_ * __half2float(h_[3]); \
            ACC[4] += v_ * __half2float(h_[4]); \
            ACC[5] += v_ * __half2float(h_[5]); \
            ACC[6] += v_ * __half2float(h_[6]); \
            ACC[7] += v_ * __half2float(h_[7]); \
        } while (0)

        const int dm = max(deg0, deg1);
        for (int k = 0; k < dm; k += 8) {
            const int meA = k + g, meB = k + 4 + g;
            const unsigned q00 = __shfl(p0, meA), q01 = __shfl(p0, meB);
            const unsigned q10 = __shfl(p1, meA), q11 = __shfl(p1, meB);
            const bool a00 = meA < deg0, a01 = meB < deg0;
            const bool a10 = meA < deg1, a11 = meB < deg1;
            float4 r00, r01, r10, r11;
            if (a00) r00 = e4[(size_t)(q00 & 0x1FFFFu)*16 + sl];
            if (a01) r01 = e4[(size_t)(q01 & 0x1FFFFu)*16 + sl];
            if (a10) r10 = e4[(size_t)(q10 & 0x1FFFFu)*16 + sl];
            if (a11) r11 = e4[(size_t)(q11 & 0x1FFFFu)*16 + sl];
            if (a00) UFMA(accA, r00, q00);
            if (a01) UFMA(accA, r01, q01);
            if (a10) UFMA(accB, r10, q10);
            if (a11) UFMA(accB, r11, q11);
        }
#undef UFMA

        #pragma unroll
        for (int j = 0; j < 8; ++j) {
            accA[j] += __shfl_xor(accA[j], 16);
            accA[j] += __shfl_xor(accA[j], 32);
            accB[j] += __shfl_xor(accB[j], 16);
            accB[j] += __shfl_xor(accB[j], 32);
        }
        // transpose: sl-layout (16 lanes x 8 dims) -> float2 layout (64 x 2)
        if (g == 0) {
            #pragma unroll
            for (int j = 0; j < 8; ++j) tr[wv][0][sl*8 + j] = accA[j];
        } else if (g == 1) {
            #pragma unroll
            for (int j = 0; j < 8; ++j) tr[wv][1][sl*8 + j] = accB[j];
        }
        __syncthreads();
        const float s00 = tr[wv][0][2*lane], s01 = tr[wv][0][2*lane + 1];
        const float s10 = tr[wv][1][2*lane], s11 = tr[wv][1][2*lane + 1];

        const size_t o0 = (size_t)row0*64 + lane;
        const size_t o1 = (size_t)row1*64 + lane;
        const float2 up0 = u_prev[o0];
        const float2 up1 = u_prev[o1];
        float dot0[N_INT], dot1[N_INT];
        #pragma unroll
        for (int i = 0; i < N_INT; ++i) {
            float2 w = s_i2[i*64 + lane];
            float pr0 = up0.x*w.x + up0.y*w.y;
            float pr1 = up1.x*w.x + up1.y*w.y;
            #pragma unroll
            for (int o = 32; o > 0; o >>= 1) {
                pr0 += __shfl_xor(pr0, o);
                pr1 += __shfl_xor(pr1, o);
            }
            dot0[i] = pr0; dot1[i] = pr1;
        }
        float m0 = dot0[0], m1 = dot1[0];
        #pragma unroll
        for (int i = 1; i < N_INT; ++i) { m0 = fmaxf(m0, dot0[i]); m1 = fmaxf(m1, dot1[i]); }
        float sm0 = 0.f, sm1 = 0.f;
        #pragma unroll
        for (int i = 0; i < N_INT; ++i) {
            dot0[i] = expf(dot0[i] - m0); sm0 += dot0[i];
            dot1[i] = expf(dot1[i] - m1); sm1 += dot1[i];
        }
        float f00 = 0.f, f01 = 0.f, f10 = 0.f, f11 = 0.f;
        #pragma unroll
        for (int i = 0; i < N_INT; ++i) {
            float a0 = dot0[i] / sm0;
            float a1 = dot1[i] / sm1;
            float2 w = s_i2[i*64 + lane];
            f00 += a0*w.x; f01 += a0*w.y;
            f10 += a1*w.x; f11 += a1*w.y;
        }
        float x00 = s00 * (1.0f + f00), x01 = s01 * (1.0f + f01);
        float x10 = s10 * (1.0f + f10), x11 = s11 * (1.0f + f11);
        float ss0 = x00*x00 + x01*x01;
        float ss1 = x10*x10 + x11*x11;
        #pragma unroll
        for (int o = 32; o > 0; o >>= 1) {
            ss0 += __shfl_xor(ss0, o);
            ss1 += __shfl_xor(ss1, o);
        }
        const float invn0 = 1.0f / fmaxf(sqrtf(ss0), 1e-12f);
        const float invn1 = 1.0f / fmaxf(sqrtf(ss1), 1e-12f);
        x00 *= invn0; x01 *= invn0;
        x10 *= invn1; x11 *= invn1;
        if (store) {
            u_out[o0] = make_float2(x00, x01);
            u_out[o1] = make_float2(x10, x11);
        }
        if (write_res) {
            float2 b0 = base_u[o0];
            float2 b1 = base_u[o1];
            res_u[o0] = make_float2(b0.x + up0.x + x00, b0.y + up0.y + x01);
            res_u[o1] = make_float2(b1.x + up1.x + x10, b1.y + up1.y + x11);
        }
    }
}

// ---------------------------------------------------------------------------
extern "C" void kernel_launch(void* const* d_in, const int* in_sizes, int n_in,
                              void* d_out, int out_size, void* d_ws, size_t ws_size,
                              hipStream_t stream) {
    const float* user_emb   = (const float*)d_in[0];
    const float* entity_emb = (const float*)d_in[1];
    const float* intent_emb = (const float*)d_in[2];
    const int*   edge_index = (const int*)  d_in[3];
    const int*   edge_type  = (const int*)  d_in[4];
    const int*   irows      = (const int*)  d_in[5];
    const int*   icols      = (const int*)  d_in[6];
    const float* ivals      = (const float*)d_in[7];
    const float* r_emb      = (const float*)d_in[8];

    float* out     = (float*)d_out;
    float* res_e   = out;
    float* res_u   = out + (size_t)N_ENT*EMB;
    float* out_cor = out + (size_t)N_ENT*EMB + (size_t)N_USERS*EMB;

    const int* head = edge_index;
    const int* tail = edge_index + N_EDGES;

    char* ws = (char*)d_ws;
    __half2* entF16 = (__half2*)ws;  ws += (size_t)N_ENT*EMB*2;
    __half2* eA     = (__half2*)ws;  ws += (size_t)N_ENT*EMB*2;
    float2*  uA     = (float2*)ws;   ws += (size_t)N_USERS*EMB*4;
    int*     sorted_e = (int*)ws;    ws += (size_t)N_ENT*SLOT*4;
    unsigned* sorted_u = (unsigned*)ws; ws += (size_t)N_USERS*SLOT*4;
    // ---- contiguous zero-region: one memset covers cnt_e|cnt_u|done
    char* zbase = ws;
    int* cnt_e = (int*)ws;           ws += (size_t)N_ENT*4;
    int* cnt_u = (int*)ws;           ws += (size_t)N_USERS*4;
    int* done   = (int*)ws;          ws += 128;
    size_t zbytes = (size_t)(ws - zbase);
    // ----
    float* i2  = (float*)ws;         ws += N_INT*EMB*4;
    float* ws_cor = (float*)ws;      ws += 16*4;

    hipMemsetAsync(zbase, 0, zbytes, stream);

    // one mega-launch: cor(10) + intent2(5) + direct build(2048) + conv(3125)
    misc_kernel<<<MISCGRID, 256, 0, stream>>>(intent_emb, r_emb, i2,
                                              ws_cor, out_cor, done,
                                              (const float2*)entity_emb, entF16,
                                              head, tail, edge_type,
                                              irows, icols, ivals,
                                              cnt_e, cnt_u, sorted_e, sorted_u);

    const float2* ent2 = (const float2*)entity_emb;
    const float2* usr2 = (const float2*)user_emb;

    // hop 1 (fused e+u): store eA(f16)/uA(f32), no residual traffic
    gather_eu_kernel<<<EBLOCKS + UBLOCKS, 256, 0, stream>>>(
        entF16, cnt_e, sorted_e, r_emb, ent2, (float2*)res_e, eA,
        cnt_u, sorted_u, usr2, i2, usr2, (float2*)res_u, uA, 1, 0);

    // hop 2 (fused e+u): res = base + prev + x
    gather_eu_kernel<<<EBLOCKS + UBLOCKS, 256, 0, stream>>>(
        eA, cnt_e, sorted_e, r_emb, ent2, (float2*)res_e, eA,
        cnt_u, sorted_u, (const float2*)uA, i2, usr2, (float2*)res_u, uA, 0, 1);
}